// Round 9
// baseline (418.041 us; speedup 1.0000x reference)
//
#include <hip/hip_runtime.h>

// ---------------------------------------------------------------------------
// EncoderDecoderAttentionHead. All GEMMs as A[M,K] @ B[N,K]^T, bf16 MFMA
// 16x16x32. R9: 256-thread / 4-wave blocks, BM=BN=128, ring-4 LDS of 16KB
// slots (64KB total) -> 2 blocks/CU. Co-resident blocks are not barrier-
// synced, so one block's ds_read bursts overlap the other's MFMA clusters
// (R8 measured wall = MFMA + LDS serialized within a lockstep block).
// 2-phase K-tile, counted vmcnt(4)/lgkmcnt, conflict-free granule swizzle
// (slot = chunk ^ ((row>>1)&3)), setprio, XCD+supertile block swizzle.
// ---------------------------------------------------------------------------

typedef __attribute__((ext_vector_type(8))) __bf16 bf16x8;
typedef __attribute__((ext_vector_type(4))) float f32x4;
typedef __attribute__((ext_vector_type(8))) unsigned short ushort8v;

#define S_DIM 4096
#define T_DIM 4096
#define D_DIM 2048

__device__ __forceinline__ unsigned short f2bf(float f) {
    unsigned int u = __float_as_uint(f);
    u += 0x7fffu + ((u >> 16) & 1u);
    return (unsigned short)(u >> 16);
}

__device__ __forceinline__ void block_sync() {
    __builtin_amdgcn_sched_barrier(0);
    __builtin_amdgcn_s_barrier();
    __builtin_amdgcn_sched_barrier(0);
}

#define GL(gptr, sptr)                                                        \
    __builtin_amdgcn_global_load_lds(                                         \
        (__attribute__((address_space(1))) void*)(void*)(gptr),               \
        (__attribute__((address_space(3))) void*)(sptr), 16, 0, 0)

__device__ __forceinline__ f32x4 MFMA16(bf16x8 a, bf16x8 b, f32x4 c) {
    return __builtin_amdgcn_mfma_f32_16x16x32_bf16(a, b, c, 0, 0, 0);
}

// ---- f32 -> bf16 convert ---------------------------------------------------
__global__ __launch_bounds__(256)
void k_convert(const float* __restrict__ in, unsigned short* __restrict__ out, long n) {
    long i = ((long)blockIdx.x * blockDim.x + threadIdx.x) * 8;
    const long stride = (long)gridDim.x * blockDim.x * 8;
    for (; i < n; i += stride) {
        float4 a = *(const float4*)(in + i);
        float4 b = *(const float4*)(in + i + 4);
        ushort8v o;
        o[0] = f2bf(a.x); o[1] = f2bf(a.y); o[2] = f2bf(a.z); o[3] = f2bf(a.w);
        o[4] = f2bf(b.x); o[5] = f2bf(b.y); o[6] = f2bf(b.z); o[7] = f2bf(b.w);
        *(ushort8v*)(out + i) = o;
    }
}

// ---- fused: x f32 [R][C] -> bf16 x^T [C][R] AND bf16 x [R][C] ---------------
__global__ __launch_bounds__(256)
void k_transpose_dual(const float* __restrict__ in,
                      unsigned short* __restrict__ outT,
                      unsigned short* __restrict__ outN, int R, int C) {
    __shared__ float tile[32][33];
    const int bx = blockIdx.x * 32;
    const int by = blockIdx.y * 32;
    const int tx = threadIdx.x;
    const int ty = threadIdx.y;
    #pragma unroll
    for (int i = 0; i < 32; i += 8) {
        float v = in[(long)(by + ty + i) * C + bx + tx];
        tile[ty + i][tx] = v;
        outN[(long)(by + ty + i) * C + bx + tx] = f2bf(v);
    }
    __syncthreads();
    #pragma unroll
    for (int i = 0; i < 32; i += 8)
        outT[(long)(bx + ty + i) * R + by + tx] = f2bf(tile[tx][ty + i]);
}

// ---- transpose bf16 [R][C] -> bf16 [C][R] ----------------------------------
__global__ __launch_bounds__(256)
void k_transpose_bf(const unsigned short* __restrict__ in,
                    unsigned short* __restrict__ out, int R, int C) {
    __shared__ unsigned short tile[32][33];
    const int bx = blockIdx.x * 32;
    const int by = blockIdx.y * 32;
    const int tx = threadIdx.x;
    const int ty = threadIdx.y;
    #pragma unroll
    for (int i = 0; i < 32; i += 8)
        tile[ty + i][tx] = in[(long)(by + ty + i) * C + bx + tx];
    __syncthreads();
    #pragma unroll
    for (int i = 0; i < 32; i += 8)
        out[(long)(bx + ty + i) * R + by + tx] = tile[tx][ty + i];
}

// ---- segment: one K-tile (BK=32), two phases of 8 MFMA ----------------------
// P0: ds B23(cur); stage A(t+3) x2; BAR; lgkm(2); MFMA n=0,1
// P1: ds A(t+1) x4 + B01(t+1) x2 from nxt; stage B(t+3) x2; vm; BAR;
//     lgkm(6); MFMA n=2,3
template<bool STG, bool PF, int VMW>
__device__ __forceinline__ void seg4(
    const unsigned short* (&gA)[2], const int (&ldA)[2],
    const unsigned short* (&gB)[2], const int (&ldB)[2],
    const char* cur, const char* nxt, char* stg, int arB, int brB,
    bf16x8 (&Ac)[4], bf16x8 (&B01c)[2], bf16x8 (&B23)[2],
    bf16x8 (&An)[4], bf16x8 (&B01n)[2],
    f32x4 (&acc)[4][4])
{
    // ---------------- phase 0 ----------------
    B23[0] = *(const bf16x8*)(cur + brB + 2048);
    B23[1] = *(const bf16x8*)(cur + brB + 3072);
    if constexpr (STG) {
        GL(gA[0], stg + ldA[0]); gA[0] += 32;
        GL(gA[1], stg + ldA[1]); gA[1] += 32;
    }
    block_sync();
    asm volatile("s_waitcnt lgkmcnt(2)" ::: "memory");
    __builtin_amdgcn_sched_barrier(0);
    __builtin_amdgcn_s_setprio(1);
    #pragma unroll
    for (int m = 0; m < 4; ++m) {
        acc[m][0] = MFMA16(Ac[m], B01c[0], acc[m][0]);
        acc[m][1] = MFMA16(Ac[m], B01c[1], acc[m][1]);
    }
    __builtin_amdgcn_s_setprio(0);
    // ---------------- phase 1 ----------------
    if constexpr (PF) {
        #pragma unroll
        for (int m = 0; m < 4; ++m)
            An[m] = *(const bf16x8*)(nxt + arB + m * 1024);
        B01n[0] = *(const bf16x8*)(nxt + brB);
        B01n[1] = *(const bf16x8*)(nxt + brB + 1024);
    }
    if constexpr (STG) {
        GL(gB[0], stg + ldB[0]); gB[0] += 32;
        GL(gB[1], stg + ldB[1]); gB[1] += 32;
    }
    if constexpr (VMW == 4)      asm volatile("s_waitcnt vmcnt(4)" ::: "memory");
    else if constexpr (VMW == 0) asm volatile("s_waitcnt vmcnt(0)" ::: "memory");
    block_sync();
    if constexpr (PF) asm volatile("s_waitcnt lgkmcnt(6)" ::: "memory");
    else              asm volatile("s_waitcnt lgkmcnt(0)" ::: "memory");
    __builtin_amdgcn_sched_barrier(0);
    __builtin_amdgcn_s_setprio(1);
    #pragma unroll
    for (int m = 0; m < 4; ++m) {
        acc[m][2] = MFMA16(Ac[m], B23[0], acc[m][2]);
        acc[m][3] = MFMA16(Ac[m], B23[1], acc[m][3]);
    }
    __builtin_amdgcn_s_setprio(0);
}

// ---- pipelined bf16 GEMM, C[M,N] = alpha*A[M,K]@B[N,K]^T (+bias[col]) ------
// BM = BN = 128, BK = 32, 4 waves (2Mx2N), wave tile 64x64, 2 blocks/CU.
// LDS rows are 64B; granule (R,s) holds chunk s^((R>>1)&3) -> conflict-free.
template<int OUT_BF16, int HAS_BIAS>
__global__ __launch_bounds__(256, 2)
void k_gemm(const unsigned short* __restrict__ A,
            const unsigned short* __restrict__ B,
            const float* __restrict__ bias,
            void* __restrict__ C,
            int M, int N, int K, float alpha) {
    constexpr int LDSA = 128 * 64;           // A region bytes (8KB)
    constexpr int SLOT = LDSA + 8192;        // + B region (8KB) = 16KB
    extern __shared__ __align__(16) char smem[];

    const int tid = threadIdx.x;
    const int l = tid & 63;
    const int w = tid >> 6;                  // 0..3
    const int wr = w >> 1;                   // 0..1
    const int wc = w & 1;                    // 0..1

    // XCD-chunked + 4-col supertile block swizzle (nwg%8==0, gx%4==0)
    const int gx = gridDim.x, gy = gridDim.y;
    const int flat = blockIdx.y * gx + blockIdx.x;
    const int per = (gx * gy) >> 3;
    const int wid = (flat & 7) * per + (flat >> 3);
    const int sc = wid / (gy * 4);
    const int rm = wid - sc * gy * 4;
    const int by = rm >> 2;
    const int bx = sc * 4 + (rm & 3);

    const long brow = (long)by * 128;
    const long bcol = (long)bx * 128;
    const int NT = K >> 5;

    // staging: granule q in [0,512) -> LDS byte q*16; row R=q>>2, slot s=q&3,
    // source chunk c = s ^ ((R>>1)&3). 2 A-loads + 2 B-loads per thread/tile.
    const unsigned short* gA[2];
    int ldA[2];
    #pragma unroll
    for (int j = 0; j < 2; ++j) {
        const int q = (w * 2 + j) * 64 + l;
        const int R = q >> 2;
        const int c = (q & 3) ^ ((R >> 1) & 3);
        gA[j] = A + (brow + R) * (long)K + c * 8;
        ldA[j] = q * 16;
    }
    const unsigned short* gB[2];
    int ldB[2];
    #pragma unroll
    for (int j = 0; j < 2; ++j) {
        const int q = (w * 2 + j) * 64 + l;
        const int R = q >> 2;
        const int c = (q & 3) ^ ((R >> 1) & 3);
        gB[j] = B + (bcol + R) * (long)K + c * 8;
        ldB[j] = LDSA + q * 16;
    }

    // ds_read bases: frag row = base + (l&15), chunk = l>>4,
    // byte = row*64 + ((chunk ^ ((row>>1)&3))<<4); frag step = 16 rows = 1024B
    const int sAB = (((l >> 4) ^ ((l >> 1) & 3)) << 4);
    const int arB = (wr * 64 + (l & 15)) * 64 + sAB;
    const int brB = LDSA + (wc * 64 + (l & 15)) * 64 + sAB;

    char* const b0 = smem;
    char* const b1 = smem + SLOT;
    char* const b2 = smem + 2 * SLOT;
    char* const b3 = smem + 3 * SLOT;

    // prologue: stage tiles 0,1,2 into slots 0,1,2; ensure 0 AND 1 landed
    {
        char* d = smem;
        #pragma unroll
        for (int tt = 0; tt < 3; ++tt) {
            #pragma unroll
            for (int j = 0; j < 2; ++j) { GL(gA[j], d + ldA[j]); gA[j] += 32; }
            #pragma unroll
            for (int j = 0; j < 2; ++j) { GL(gB[j], d + ldB[j]); gB[j] += 32; }
            d += SLOT;
        }
        asm volatile("s_waitcnt vmcnt(4)" ::: "memory");
        block_sync();
    }

    bf16x8 Aa[4], Ab[4], Ba[2], Bb[2], B23[2];
    #pragma unroll
    for (int m = 0; m < 4; ++m) Aa[m] = *(const bf16x8*)(b0 + arB + m * 1024);
    Ba[0] = *(const bf16x8*)(b0 + brB);
    Ba[1] = *(const bf16x8*)(b0 + brB + 1024);

    f32x4 acc[4][4] = {};
    for (int t = 0; t + 8 <= NT; t += 4) {
        seg4<true, true, 4>(gA, ldA, gB, ldB, b0, b1, b3, arB, brB,
                            Aa, Ba, B23, Ab, Bb, acc);
        seg4<true, true, 4>(gA, ldA, gB, ldB, b1, b2, b0, arB, brB,
                            Ab, Bb, B23, Aa, Ba, acc);
        seg4<true, true, 4>(gA, ldA, gB, ldB, b2, b3, b1, arB, brB,
                            Aa, Ba, B23, Ab, Bb, acc);
        seg4<true, true, 4>(gA, ldA, gB, ldB, b3, b0, b2, arB, brB,
                            Ab, Bb, B23, Aa, Ba, acc);
    }
    // tail: tiles NT-4 .. NT-1
    seg4<true,  true,  4>(gA, ldA, gB, ldB, b0, b1, b3, arB, brB,
                          Aa, Ba, B23, Ab, Bb, acc);
    seg4<false, true,  0>(gA, ldA, gB, ldB, b1, b2, b3, arB, brB,
                          Ab, Bb, B23, Aa, Ba, acc);
    seg4<false, true, -1>(gA, ldA, gB, ldB, b2, b3, b3, arB, brB,
                          Aa, Ba, B23, Ab, Bb, acc);
    seg4<false, false, -1>(gA, ldA, gB, ldB, b3, b0, b3, arB, brB,
                           Ab, Bb, B23, Aa, Ba, acc);

    // epilogue: C/D layout col = lane&15, row = (lane>>4)*4 + reg
    const long crow0 = brow + wr * 64 + (l >> 4) * 4;
    const long ccol0 = bcol + wc * 64 + (l & 15);
    #pragma unroll
    for (int n = 0; n < 4; ++n) {
        const long col = ccol0 + n * 16;
        const float bb = HAS_BIAS ? bias[col] : 0.0f;
        #pragma unroll
        for (int m = 0; m < 4; ++m) {
            #pragma unroll
            for (int r = 0; r < 4; ++r) {
                const long row = crow0 + m * 16 + r;
                const float v = acc[m][n][r] * alpha + bb;
                if (OUT_BF16)
                    ((unsigned short*)C)[row * N + col] = f2bf(v);
                else
                    ((float*)C)[row * N + col] = v;
            }
        }
    }
}

// ---- row softmax: e [S][T] bf16 -> a [S][T] bf16 ----------------------------
__global__ __launch_bounds__(256)
void k_softmax_bf(const unsigned short* __restrict__ E,
                  unsigned short* __restrict__ A, int T) {
    const long row = blockIdx.x;
    const unsigned short* er = E + row * (long)T;
    const int t = threadIdx.x;
    const int l = t & 63;
    const int w = t >> 6;

    float v[16];
    float m = -3.4e38f;
    #pragma unroll
    for (int j = 0; j < 2; ++j) {
        ushort8v u = *(const ushort8v*)(er + j * 2048 + t * 8);
        #pragma unroll
        for (int i = 0; i < 8; ++i) {
            v[j * 8 + i] = __uint_as_float((unsigned int)u[i] << 16);
            m = fmaxf(m, v[j * 8 + i]);
        }
    }
    #pragma unroll
    for (int o = 32; o > 0; o >>= 1) m = fmaxf(m, __shfl_xor(m, o));

    __shared__ float redm[4];
    __shared__ float reds[4];
    if (l == 0) redm[w] = m;
    __syncthreads();
    m = fmaxf(fmaxf(redm[0], redm[1]), fmaxf(redm[2], redm[3]));

    float s = 0.f;
    #pragma unroll
    for (int i = 0; i < 16; ++i) {
        v[i] = __expf(v[i] - m);
        s += v[i];
    }
    #pragma unroll
    for (int o = 32; o > 0; o >>= 1) s += __shfl_xor(s, o);
    if (l == 0) reds[w] = s;
    __syncthreads();
    s = reds[0] + reds[1] + reds[2] + reds[3];
    const float inv = 1.0f / s;

    unsigned short* ar = A + row * (long)T;
    #pragma unroll
    for (int j = 0; j < 2; ++j) {
        ushort8v o8;
        #pragma unroll
        for (int i = 0; i < 8; ++i) o8[i] = f2bf(v[j * 8 + i] * inv);
        *(ushort8v*)(ar + j * 2048 + t * 8) = o8;
    }
}

// ---------------------------------------------------------------------------
extern "C" void kernel_launch(void* const* d_in, const int* in_sizes, int n_in,
                              void* d_out, int out_size, void* d_ws, size_t ws_size,
                              hipStream_t stream) {
    const float* x   = (const float*)d_in[0];   // [S][D]
    const float* enc = (const float*)d_in[1];   // [2][T][S]
    const float* Wq  = (const float*)d_in[2];   // [D][D]
    const float* bq  = (const float*)d_in[3];   // [D]
    float* out = (float*)d_out;                 // [S][D]
    char* ws = (char*)d_ws;

    // abf overlaps xT/xbf (dead before softmax). e (bf16) overlaps encbf.
    unsigned short* abf   = (unsigned short*)(ws);                 // [S][T]   32MB (late)
    unsigned short* xT    = (unsigned short*)(ws);                 // [D][S]   16MB (early)
    unsigned short* xbf   = (unsigned short*)(ws + (16L << 20));   // [S][D]   16MB (early)
    unsigned short* wqbf  = (unsigned short*)(ws + (32L << 20));   // [D][D]    8MB
    unsigned short* qbf   = (unsigned short*)(ws + (40L << 20));   // [S][D]   16MB
    unsigned short* kv    = (unsigned short*)(ws + (56L << 20));   // [2T][D]  32MB
    unsigned short* vT    = (unsigned short*)(ws + (88L << 20));   // [D][T]   16MB
    unsigned short* encbf = (unsigned short*)(ws + (104L << 20));  // [2][T][S] 64MB (early)
    unsigned short* ebf   = (unsigned short*)(ws + (104L << 20));  // [S][T]   32MB (reuse)

    k_convert<<<4096, 256, 0, stream>>>(Wq,  wqbf,  (long)D_DIM * D_DIM);
    k_convert<<<4096, 256, 0, stream>>>(enc, encbf, 2L * T_DIM * S_DIM);
    k_transpose_dual<<<dim3(D_DIM / 32, S_DIM / 32), dim3(32, 8), 0, stream>>>(
        x, xT, xbf, S_DIM, D_DIM);

    #define LAUNCH_G(OB, HB, Ap, Bp, biasp, Cp, M_, N_, K_, al)                            \
        do {                                                                               \
            constexpr int smemB = 4 * (128 * 64 + 8192);                                   \
            hipFuncSetAttribute((const void*)k_gemm<OB, HB>,                               \
                                hipFuncAttributeMaxDynamicSharedMemorySize, smemB);        \
            k_gemm<OB, HB><<<dim3((N_) / 128, (M_) / 128), 256, smemB, stream>>>(          \
                Ap, Bp, biasp, Cp, M_, N_, K_, al);                                        \
        } while (0)

    // q = x @ Wq^T + bq            [4096,2048]  grid (16,32) = 512
    LAUNCH_G(1, 1, xbf, wqbf, bq, qbf, S_DIM, D_DIM, D_DIM, 1.0f);
    // kv = enc @ xT^T (k rows 0..T-1, v rows T..2T-1)  [8192,2048]  grid (16,64)
    LAUNCH_G(1, 0, encbf, xT, nullptr, kv, 2 * T_DIM, D_DIM, S_DIM, 1.0f);
    // vT = transpose(v)            [2048,4096]
    k_transpose_bf<<<dim3(D_DIM / 32, T_DIM / 32), dim3(32, 8), 0, stream>>>(
        kv + (long)T_DIM * D_DIM, vT, T_DIM, D_DIM);
    // e = q @ k^T / sqrt(D)        [4096,4096]  grid (32,32), bf16 out
    LAUNCH_G(1, 0, qbf, kv, nullptr, ebf, S_DIM, T_DIM, D_DIM, 0.022097086912079608f);
    // a = softmax(e)               [S,T] bf16
    k_softmax_bf<<<S_DIM, 256, 0, stream>>>(ebf, abf, T_DIM);
    // z = a @ vT^T                 [4096,2048]  grid (16,32), fp32 -> d_out
    LAUNCH_G(0, 0, abf, vT, nullptr, out, S_DIM, D_DIM, T_DIM, 1.0f);
}

// Round 10
// 364.828 us; speedup vs baseline: 1.1459x; 1.1459x over previous
//
#include <hip/hip_runtime.h>

// ---------------------------------------------------------------------------
// EncoderDecoderAttentionHead. All GEMMs as A[M,K] @ B[N,K]^T, bf16 MFMA
// 16x16x32. R10 = R8 layout/traffic with a restructured K-tile: ONE barrier
// per tile, and all next-tile ds_reads + global_load_lds staged INSIDE the
// MFMA cluster (R8 measured wall = LDS-port time + MFMA time serialized by
// the read-burst/MFMA-burst lockstep; interleaving lets the port hide).
// Ring-4 LDS, BK=32, counted vmcnt/lgkmcnt, conflict-free granule swizzle
// (slot = chunk ^ ((row>>1)&3)), setprio, XCD+supertile block swizzle.
// ---------------------------------------------------------------------------

typedef __attribute__((ext_vector_type(8))) __bf16 bf16x8;
typedef __attribute__((ext_vector_type(4))) float f32x4;
typedef __attribute__((ext_vector_type(8))) unsigned short ushort8v;

#define S_DIM 4096
#define T_DIM 4096
#define D_DIM 2048

__device__ __forceinline__ unsigned short f2bf(float f) {
    unsigned int u = __float_as_uint(f);
    u += 0x7fffu + ((u >> 16) & 1u);
    return (unsigned short)(u >> 16);
}

__device__ __forceinline__ void block_sync() {
    __builtin_amdgcn_sched_barrier(0);
    __builtin_amdgcn_s_barrier();
    __builtin_amdgcn_sched_barrier(0);
}

#define GL(gptr, sptr)                                                        \
    __builtin_amdgcn_global_load_lds(                                         \
        (__attribute__((address_space(1))) void*)(void*)(gptr),               \
        (__attribute__((address_space(3))) void*)(sptr), 16, 0, 0)

__device__ __forceinline__ f32x4 MFMA16(bf16x8 a, bf16x8 b, f32x4 c) {
    return __builtin_amdgcn_mfma_f32_16x16x32_bf16(a, b, c, 0, 0, 0);
}

// ---- f32 -> bf16 convert ---------------------------------------------------
__global__ __launch_bounds__(256)
void k_convert(const float* __restrict__ in, unsigned short* __restrict__ out, long n) {
    long i = ((long)blockIdx.x * blockDim.x + threadIdx.x) * 8;
    const long stride = (long)gridDim.x * blockDim.x * 8;
    for (; i < n; i += stride) {
        float4 a = *(const float4*)(in + i);
        float4 b = *(const float4*)(in + i + 4);
        ushort8v o;
        o[0] = f2bf(a.x); o[1] = f2bf(a.y); o[2] = f2bf(a.z); o[3] = f2bf(a.w);
        o[4] = f2bf(b.x); o[5] = f2bf(b.y); o[6] = f2bf(b.z); o[7] = f2bf(b.w);
        *(ushort8v*)(out + i) = o;
    }
}

// ---- fused: x f32 [R][C] -> bf16 x^T [C][R] AND bf16 x [R][C] ---------------
__global__ __launch_bounds__(256)
void k_transpose_dual(const float* __restrict__ in,
                      unsigned short* __restrict__ outT,
                      unsigned short* __restrict__ outN, int R, int C) {
    __shared__ float tile[32][33];
    const int bx = blockIdx.x * 32;
    const int by = blockIdx.y * 32;
    const int tx = threadIdx.x;
    const int ty = threadIdx.y;
    #pragma unroll
    for (int i = 0; i < 32; i += 8) {
        float v = in[(long)(by + ty + i) * C + bx + tx];
        tile[ty + i][tx] = v;
        outN[(long)(by + ty + i) * C + bx + tx] = f2bf(v);
    }
    __syncthreads();
    #pragma unroll
    for (int i = 0; i < 32; i += 8)
        outT[(long)(bx + ty + i) * R + by + tx] = f2bf(tile[tx][ty + i]);
}

// ---- transpose bf16 [R][C] -> bf16 [C][R] ----------------------------------
__global__ __launch_bounds__(256)
void k_transpose_bf(const unsigned short* __restrict__ in,
                    unsigned short* __restrict__ out, int R, int C) {
    __shared__ unsigned short tile[32][33];
    const int bx = blockIdx.x * 32;
    const int by = blockIdx.y * 32;
    const int tx = threadIdx.x;
    const int ty = threadIdx.y;
    #pragma unroll
    for (int i = 0; i < 32; i += 8)
        tile[ty + i][tx] = in[(long)(by + ty + i) * C + bx + tx];
    __syncthreads();
    #pragma unroll
    for (int i = 0; i < 32; i += 8)
        out[(long)(bx + ty + i) * R + by + tx] = tile[tx][ty + i];
}

// ---- MFR=8 tile: one barrier, one interleaved cluster -----------------------
// top: vm(VMW); BAR; lgkm(0). Cluster: B23c reads; MFMA n=0,1 interleaved
// with stage(t+3) gloads + next-tile frag reads; lgkm(10); MFMA n=2,3.
template<bool STG, bool PF, int VMW>
__device__ __forceinline__ void seg8(
    const unsigned short* (&gA)[2], const int (&ldA)[2],
    const unsigned short* (&gB)[2], const int (&ldB)[2],
    const char* cur, const char* nxt, char* stg, int arB, int brB,
    bf16x8 (&Ac)[8], bf16x8 (&B01c)[2], bf16x8 (&B23)[2],
    bf16x8 (&An)[8], bf16x8 (&B01n)[2],
    f32x4 (&acc)[8][4])
{
    if constexpr (VMW == 4)      asm volatile("s_waitcnt vmcnt(4)" ::: "memory");
    else if constexpr (VMW == 0) asm volatile("s_waitcnt vmcnt(0)" ::: "memory");
    block_sync();
    asm volatile("s_waitcnt lgkmcnt(0)" ::: "memory");
    __builtin_amdgcn_sched_barrier(0);

    // B23 of current tile (consumed in second half of this cluster)
    B23[0] = *(const bf16x8*)(cur + brB + 2048);
    B23[1] = *(const bf16x8*)(cur + brB + 3072);

    __builtin_amdgcn_s_setprio(1);
    // ---- first half: n=0,1 interleaved with next-tile reads + staging ----
    acc[0][0] = MFMA16(Ac[0], B01c[0], acc[0][0]);
    acc[0][1] = MFMA16(Ac[0], B01c[1], acc[0][1]);
    acc[1][0] = MFMA16(Ac[1], B01c[0], acc[1][0]);
    acc[1][1] = MFMA16(Ac[1], B01c[1], acc[1][1]);
    if constexpr (STG) { GL(gA[0], stg + ldA[0]); gA[0] += 32; }
    if constexpr (PF) {
        An[0] = *(const bf16x8*)(nxt + arB);
        An[1] = *(const bf16x8*)(nxt + arB + 1024);
    }
    acc[2][0] = MFMA16(Ac[2], B01c[0], acc[2][0]);
    acc[2][1] = MFMA16(Ac[2], B01c[1], acc[2][1]);
    acc[3][0] = MFMA16(Ac[3], B01c[0], acc[3][0]);
    acc[3][1] = MFMA16(Ac[3], B01c[1], acc[3][1]);
    if constexpr (STG) { GL(gA[1], stg + ldA[1]); gA[1] += 32; }
    if constexpr (PF) {
        An[2] = *(const bf16x8*)(nxt + arB + 2048);
        An[3] = *(const bf16x8*)(nxt + arB + 3072);
    }
    acc[4][0] = MFMA16(Ac[4], B01c[0], acc[4][0]);
    acc[4][1] = MFMA16(Ac[4], B01c[1], acc[4][1]);
    acc[5][0] = MFMA16(Ac[5], B01c[0], acc[5][0]);
    acc[5][1] = MFMA16(Ac[5], B01c[1], acc[5][1]);
    if constexpr (STG) { GL(gB[0], stg + ldB[0]); gB[0] += 32; }
    if constexpr (PF) {
        An[4] = *(const bf16x8*)(nxt + arB + 4096);
        An[5] = *(const bf16x8*)(nxt + arB + 5120);
    }
    acc[6][0] = MFMA16(Ac[6], B01c[0], acc[6][0]);
    acc[6][1] = MFMA16(Ac[6], B01c[1], acc[6][1]);
    acc[7][0] = MFMA16(Ac[7], B01c[0], acc[7][0]);
    acc[7][1] = MFMA16(Ac[7], B01c[1], acc[7][1]);
    if constexpr (STG) { GL(gB[1], stg + ldB[1]); gB[1] += 32; }
    if constexpr (PF) {
        An[6] = *(const bf16x8*)(nxt + arB + 6144);
        An[7] = *(const bf16x8*)(nxt + arB + 7168);
        B01n[0] = *(const bf16x8*)(nxt + brB);
        B01n[1] = *(const bf16x8*)(nxt + brB + 1024);
    }
    // wait: B23 (issued first) drained; 10 next-tile reads stay in flight
    if constexpr (PF) asm volatile("s_waitcnt lgkmcnt(10)" ::: "memory");
    else              asm volatile("s_waitcnt lgkmcnt(0)" ::: "memory");
    __builtin_amdgcn_sched_barrier(0);
    // ---- second half: n=2,3 ----
    #pragma unroll
    for (int m = 0; m < 8; ++m) {
        acc[m][2] = MFMA16(Ac[m], B23[0], acc[m][2]);
        acc[m][3] = MFMA16(Ac[m], B23[1], acc[m][3]);
    }
    __builtin_amdgcn_s_setprio(0);
}

// ---- MFR=4 tile: same structure, 8 MFMA halves ------------------------------
template<bool STG, bool PF, int VMW>
__device__ __forceinline__ void seg4(
    const unsigned short* (&gA)[2], const int (&ldA)[2],
    const unsigned short* (&gB)[2], const int (&ldB)[2],
    const char* cur, const char* nxt, char* stg, int arB, int brB,
    bf16x8 (&Ac)[4], bf16x8 (&B01c)[2], bf16x8 (&B23)[2],
    bf16x8 (&An)[4], bf16x8 (&B01n)[2],
    f32x4 (&acc)[4][4])
{
    if constexpr (VMW == 3)      asm volatile("s_waitcnt vmcnt(3)" ::: "memory");
    else if constexpr (VMW == 0) asm volatile("s_waitcnt vmcnt(0)" ::: "memory");
    block_sync();
    asm volatile("s_waitcnt lgkmcnt(0)" ::: "memory");
    __builtin_amdgcn_sched_barrier(0);

    B23[0] = *(const bf16x8*)(cur + brB + 2048);
    B23[1] = *(const bf16x8*)(cur + brB + 3072);

    __builtin_amdgcn_s_setprio(1);
    acc[0][0] = MFMA16(Ac[0], B01c[0], acc[0][0]);
    acc[0][1] = MFMA16(Ac[0], B01c[1], acc[0][1]);
    acc[1][0] = MFMA16(Ac[1], B01c[0], acc[1][0]);
    acc[1][1] = MFMA16(Ac[1], B01c[1], acc[1][1]);
    if constexpr (STG) { GL(gA[0], stg + ldA[0]); gA[0] += 32; }
    if constexpr (PF) {
        An[0] = *(const bf16x8*)(nxt + arB);
        An[1] = *(const bf16x8*)(nxt + arB + 1024);
    }
    acc[2][0] = MFMA16(Ac[2], B01c[0], acc[2][0]);
    acc[2][1] = MFMA16(Ac[2], B01c[1], acc[2][1]);
    acc[3][0] = MFMA16(Ac[3], B01c[0], acc[3][0]);
    acc[3][1] = MFMA16(Ac[3], B01c[1], acc[3][1]);
    if constexpr (STG) {
        GL(gB[0], stg + ldB[0]); gB[0] += 32;
        GL(gB[1], stg + ldB[1]); gB[1] += 32;
    }
    if constexpr (PF) {
        An[2] = *(const bf16x8*)(nxt + arB + 2048);
        An[3] = *(const bf16x8*)(nxt + arB + 3072);
        B01n[0] = *(const bf16x8*)(nxt + brB);
        B01n[1] = *(const bf16x8*)(nxt + brB + 1024);
    }
    if constexpr (PF) asm volatile("s_waitcnt lgkmcnt(6)" ::: "memory");
    else              asm volatile("s_waitcnt lgkmcnt(0)" ::: "memory");
    __builtin_amdgcn_sched_barrier(0);
    #pragma unroll
    for (int m = 0; m < 4; ++m) {
        acc[m][2] = MFMA16(Ac[m], B23[0], acc[m][2]);
        acc[m][3] = MFMA16(Ac[m], B23[1], acc[m][3]);
    }
    __builtin_amdgcn_s_setprio(0);
}

// ---- pipelined bf16 GEMM, C[M,N] = alpha*A[M,K]@B[N,K]^T (+bias[col]) ------
// BM = MFR*32, BN = 256, BK = 32, 8 waves (2Mx4N), wave tile (MFR*16)x64.
// LDS rows are 64B; granule (R,s) holds chunk s^((R>>1)&3) -> conflict-free.
template<int MFR, int OUT_BF16, int HAS_BIAS>
__global__ __launch_bounds__(512, 2)
void k_gemm(const unsigned short* __restrict__ A,
            const unsigned short* __restrict__ B,
            const float* __restrict__ bias,
            void* __restrict__ C,
            int M, int N, int K, float alpha) {
    constexpr int BM   = MFR * 32;
    constexpr int LPTA = (BM * 4) / 512;     // A gloads/thread/tile (2 or 1)
    constexpr int LDSA = BM * 64;            // A region bytes
    constexpr int SLOT = LDSA + 16384;       // + B region (256 rows x 64B)
    extern __shared__ __align__(16) char smem[];

    const int tid = threadIdx.x;
    const int l = tid & 63;
    const int w = tid >> 6;
    const int wr = w >> 2;                   // 0..1
    const int wc = w & 3;                    // 0..3

    // XCD-chunked + 4-col supertile block swizzle (grid always 256, gx%4==0)
    const int gx = gridDim.x, gy = gridDim.y;
    const int flat = blockIdx.y * gx + blockIdx.x;
    const int per = (gx * gy) >> 3;
    const int wid = (flat & 7) * per + (flat >> 3);
    const int sc = wid / (gy * 4);
    const int rm = wid - sc * gy * 4;
    const int by = rm >> 2;
    const int bx = sc * 4 + (rm & 3);

    const long brow = (long)by * BM;
    const long bcol = (long)bx * 256;
    const int NT = K >> 5;

    // staging: granule q -> LDS byte q*16; row R=q>>2, slot s=q&3,
    // source chunk c = s ^ ((R>>1)&3)
    const unsigned short* gA[2];
    int ldA[2];
    #pragma unroll
    for (int j = 0; j < LPTA; ++j) {
        const int q = (w * LPTA + j) * 64 + l;
        const int R = q >> 2;
        const int c = (q & 3) ^ ((R >> 1) & 3);
        gA[j] = A + (brow + R) * (long)K + c * 8;
        ldA[j] = q * 16;
    }
    const unsigned short* gB[2];
    int ldB[2];
    #pragma unroll
    for (int j = 0; j < 2; ++j) {
        const int q = (w * 2 + j) * 64 + l;
        const int R = q >> 2;
        const int c = (q & 3) ^ ((R >> 1) & 3);
        gB[j] = B + (bcol + R) * (long)K + c * 8;
        ldB[j] = LDSA + q * 16;
    }

    // ds_read bases: frag row = base + (l&15), chunk = l>>4,
    // byte = row*64 + ((chunk ^ ((row>>1)&3))<<4); frag step = 16 rows = 1024B
    const int sAB = (((l >> 4) ^ ((l >> 1) & 3)) << 4);
    const int arB = (wr * (MFR * 16) + (l & 15)) * 64 + sAB;
    const int brB = LDSA + (wc * 64 + (l & 15)) * 64 + sAB;

    char* const b0 = smem;
    char* const b1 = smem + SLOT;
    char* const b2 = smem + 2 * SLOT;
    char* const b3 = smem + 3 * SLOT;

    // prologue: stage tiles 0,1,2; certify slot 0; preload tile-0 frags
    {
        char* d = smem;
        #pragma unroll
        for (int tt = 0; tt < 3; ++tt) {
            #pragma unroll
            for (int j = 0; j < LPTA; ++j) { GL(gA[j], d + ldA[j]); gA[j] += 32; }
            #pragma unroll
            for (int j = 0; j < 2; ++j)    { GL(gB[j], d + ldB[j]); gB[j] += 32; }
            d += SLOT;
        }
        if constexpr (MFR == 8) asm volatile("s_waitcnt vmcnt(8)" ::: "memory");
        else                    asm volatile("s_waitcnt vmcnt(6)" ::: "memory");
        block_sync();
    }

    if constexpr (MFR == 8) {
        bf16x8 Aa[8], Ab[8], Ba[2], Bb[2], B23[2];
        #pragma unroll
        for (int m = 0; m < 8; ++m) Aa[m] = *(const bf16x8*)(b0 + arB + m * 1024);
        Ba[0] = *(const bf16x8*)(b0 + brB);
        Ba[1] = *(const bf16x8*)(b0 + brB + 1024);

        f32x4 acc[8][4] = {};
        for (int t = 0; t + 8 <= NT; t += 4) {
            seg8<true, true, 4>(gA, ldA, gB, ldB, b0, b1, b3, arB, brB,
                                Aa, Ba, B23, Ab, Bb, acc);
            seg8<true, true, 4>(gA, ldA, gB, ldB, b1, b2, b0, arB, brB,
                                Ab, Bb, B23, Aa, Ba, acc);
            seg8<true, true, 4>(gA, ldA, gB, ldB, b2, b3, b1, arB, brB,
                                Aa, Ba, B23, Ab, Bb, acc);
            seg8<true, true, 4>(gA, ldA, gB, ldB, b3, b0, b2, arB, brB,
                                Ab, Bb, B23, Aa, Ba, acc);
        }
        // tail: tiles NT-4 .. NT-1
        seg8<true,  true,  4>(gA, ldA, gB, ldB, b0, b1, b3, arB, brB,
                              Aa, Ba, B23, Ab, Bb, acc);
        seg8<false, true,  4>(gA, ldA, gB, ldB, b1, b2, b3, arB, brB,
                              Ab, Bb, B23, Aa, Ba, acc);
        seg8<false, true,  0>(gA, ldA, gB, ldB, b2, b3, b3, arB, brB,
                              Aa, Ba, B23, Ab, Bb, acc);
        seg8<false, false, -1>(gA, ldA, gB, ldB, b3, b0, b3, arB, brB,
                               Ab, Bb, B23, Aa, Ba, acc);

        const long crow0 = brow + wr * 128 + (l >> 4) * 4;
        const long ccol0 = bcol + wc * 64 + (l & 15);
        #pragma unroll
        for (int n = 0; n < 4; ++n) {
            const long col = ccol0 + n * 16;
            const float bb = HAS_BIAS ? bias[col] : 0.0f;
            #pragma unroll
            for (int m = 0; m < 8; ++m) {
                #pragma unroll
                for (int r = 0; r < 4; ++r) {
                    const long row = crow0 + m * 16 + r;
                    const float v = acc[m][n][r] * alpha + bb;
                    if (OUT_BF16)
                        ((unsigned short*)C)[row * N + col] = f2bf(v);
                    else
                        ((float*)C)[row * N + col] = v;
                }
            }
        }
    } else {
        bf16x8 Aa[4], Ab[4], Ba[2], Bb[2], B23[2];
        #pragma unroll
        for (int m = 0; m < 4; ++m) Aa[m] = *(const bf16x8*)(b0 + arB + m * 1024);
        Ba[0] = *(const bf16x8*)(b0 + brB);
        Ba[1] = *(const bf16x8*)(b0 + brB + 1024);

        f32x4 acc[4][4] = {};
        for (int t = 0; t + 8 <= NT; t += 4) {
            seg4<true, true, 3>(gA, ldA, gB, ldB, b0, b1, b3, arB, brB,
                                Aa, Ba, B23, Ab, Bb, acc);
            seg4<true, true, 3>(gA, ldA, gB, ldB, b1, b2, b0, arB, brB,
                                Ab, Bb, B23, Aa, Ba, acc);
            seg4<true, true, 3>(gA, ldA, gB, ldB, b2, b3, b1, arB, brB,
                                Aa, Ba, B23, Ab, Bb, acc);
            seg4<true, true, 3>(gA, ldA, gB, ldB, b3, b0, b2, arB, brB,
                                Ab, Bb, B23, Aa, Ba, acc);
        }
        seg4<true,  true,  3>(gA, ldA, gB, ldB, b0, b1, b3, arB, brB,
                              Aa, Ba, B23, Ab, Bb, acc);
        seg4<false, true,  3>(gA, ldA, gB, ldB, b1, b2, b3, arB, brB,
                              Ab, Bb, B23, Aa, Ba, acc);
        seg4<false, true,  0>(gA, ldA, gB, ldB, b2, b3, b3, arB, brB,
                              Aa, Ba, B23, Ab, Bb, acc);
        seg4<false, false, -1>(gA, ldA, gB, ldB, b3, b0, b3, arB, brB,
                               Ab, Bb, B23, Aa, Ba, acc);

        const long crow0 = brow + wr * 64 + (l >> 4) * 4;
        const long ccol0 = bcol + wc * 64 + (l & 15);
        #pragma unroll
        for (int n = 0; n < 4; ++n) {
            const long col = ccol0 + n * 16;
            const float bb = HAS_BIAS ? bias[col] : 0.0f;
            #pragma unroll
            for (int m = 0; m < 4; ++m) {
                #pragma unroll
                for (int r = 0; r < 4; ++r) {
                    const long row = crow0 + m * 16 + r;
                    const float v = acc[m][n][r] * alpha + bb;
                    if (OUT_BF16)
                        ((unsigned short*)C)[row * N + col] = f2bf(v);
                    else
                        ((float*)C)[row * N + col] = v;
                }
            }
        }
    }
}

// ---- row softmax: e [S][T] bf16 -> a [S][T] bf16 ----------------------------
__global__ __launch_bounds__(256)
void k_softmax_bf(const unsigned short* __restrict__ E,
                  unsigned short* __restrict__ A, int T) {
    const long row = blockIdx.x;
    const unsigned short* er = E + row * (long)T;
    const int t = threadIdx.x;
    const int l = t & 63;
    const int w = t >> 6;

    float v[16];
    float m = -3.4e38f;
    #pragma unroll
    for (int j = 0; j < 2; ++j) {
        ushort8v u = *(const ushort8v*)(er + j * 2048 + t * 8);
        #pragma unroll
        for (int i = 0; i < 8; ++i) {
            v[j * 8 + i] = __uint_as_float((unsigned int)u[i] << 16);
            m = fmaxf(m, v[j * 8 + i]);
        }
    }
    #pragma unroll
    for (int o = 32; o > 0; o >>= 1) m = fmaxf(m, __shfl_xor(m, o));

    __shared__ float redm[4];
    __shared__ float reds[4];
    if (l == 0) redm[w] = m;
    __syncthreads();
    m = fmaxf(fmaxf(redm[0], redm[1]), fmaxf(redm[2], redm[3]));

    float s = 0.f;
    #pragma unroll
    for (int i = 0; i < 16; ++i) {
        v[i] = __expf(v[i] - m);
        s += v[i];
    }
    #pragma unroll
    for (int o = 32; o > 0; o >>= 1) s += __shfl_xor(s, o);
    if (l == 0) reds[w] = s;
    __syncthreads();
    s = reds[0] + reds[1] + reds[2] + reds[3];
    const float inv = 1.0f / s;

    unsigned short* ar = A + row * (long)T;
    #pragma unroll
    for (int j = 0; j < 2; ++j) {
        ushort8v o8;
        #pragma unroll
        for (int i = 0; i < 8; ++i) o8[i] = f2bf(v[j * 8 + i] * inv);
        *(ushort8v*)(ar + j * 2048 + t * 8) = o8;
    }
}

// ---------------------------------------------------------------------------
extern "C" void kernel_launch(void* const* d_in, const int* in_sizes, int n_in,
                              void* d_out, int out_size, void* d_ws, size_t ws_size,
                              hipStream_t stream) {
    const float* x   = (const float*)d_in[0];   // [S][D]
    const float* enc = (const float*)d_in[1];   // [2][T][S]
    const float* Wq  = (const float*)d_in[2];   // [D][D]
    const float* bq  = (const float*)d_in[3];   // [D]
    float* out = (float*)d_out;                 // [S][D]
    char* ws = (char*)d_ws;

    // abf overlaps xT/xbf (dead before softmax). e (bf16) overlaps encbf.
    unsigned short* abf   = (unsigned short*)(ws);                 // [S][T]   32MB (late)
    unsigned short* xT    = (unsigned short*)(ws);                 // [D][S]   16MB (early)
    unsigned short* xbf   = (unsigned short*)(ws + (16L << 20));   // [S][D]   16MB (early)
    unsigned short* wqbf  = (unsigned short*)(ws + (32L << 20));   // [D][D]    8MB
    unsigned short* qbf   = (unsigned short*)(ws + (40L << 20));   // [S][D]   16MB
    unsigned short* kv    = (unsigned short*)(ws + (56L << 20));   // [2T][D]  32MB
    unsigned short* vT    = (unsigned short*)(ws + (88L << 20));   // [D][T]   16MB
    unsigned short* encbf = (unsigned short*)(ws + (104L << 20));  // [2][T][S] 64MB (early)
    unsigned short* ebf   = (unsigned short*)(ws + (104L << 20));  // [S][T]   32MB (reuse)

    k_convert<<<4096, 256, 0, stream>>>(Wq,  wqbf,  (long)D_DIM * D_DIM);
    k_convert<<<4096, 256, 0, stream>>>(enc, encbf, 2L * T_DIM * S_DIM);
    k_transpose_dual<<<dim3(D_DIM / 32, S_DIM / 32), dim3(32, 8), 0, stream>>>(
        x, xT, xbf, S_DIM, D_DIM);

    #define LAUNCH_G(MFRV, OB, HB, Ap, Bp, biasp, Cp, M_, N_, K_, al)                      \
        do {                                                                               \
            constexpr int smemB = (MFRV * 32 * 64 + 16384) * 4;                            \
            hipFuncSetAttribute((const void*)k_gemm<MFRV, OB, HB>,                         \
                                hipFuncAttributeMaxDynamicSharedMemorySize, smemB);        \
            k_gemm<MFRV, OB, HB><<<dim3((N_) / 256, (M_) / (MFRV * 32)), 512, smemB,       \
                                   stream>>>(Ap, Bp, biasp, Cp, M_, N_, K_, al);           \
        } while (0)

    // q = x @ Wq^T + bq            [4096,2048]  grid (8,32)
    LAUNCH_G(4, 1, 1, xbf, wqbf, bq, qbf, S_DIM, D_DIM, D_DIM, 1.0f);
    // kv = enc @ xT^T (k rows 0..T-1, v rows T..2T-1)  [8192,2048]  grid (8,32)
    LAUNCH_G(8, 1, 0, encbf, xT, nullptr, kv, 2 * T_DIM, D_DIM, S_DIM, 1.0f);
    // vT = transpose(v)            [2048,4096]
    k_transpose_bf<<<dim3(D_DIM / 32, T_DIM / 32), dim3(32, 8), 0, stream>>>(
        kv + (long)T_DIM * D_DIM, vT, T_DIM, D_DIM);
    // e = q @ k^T / sqrt(D)        [4096,4096]  grid (16,16), bf16 out
    LAUNCH_G(8, 1, 0, qbf, kv, nullptr, ebf, S_DIM, T_DIM, D_DIM, 0.022097086912079608f);
    // a = softmax(e)               [S,T] bf16
    k_softmax_bf<<<S_DIM, 256, 0, stream>>>(ebf, abf, T_DIM);
    // z = a @ vT^T                 [4096,2048]  grid (8,32), fp32 -> d_out
    LAUNCH_G(4, 0, 0, abf, vT, nullptr, out, S_DIM, D_DIM, T_DIM, 1.0f);
}

// Round 12
// 351.356 us; speedup vs baseline: 1.1898x; 1.0383x over previous
//
#include <hip/hip_runtime.h>

// ---------------------------------------------------------------------------
// EncoderDecoderAttentionHead. All GEMMs as A[M,K] @ B[N,K]^T, bf16 MFMA
// 16x16x32. R12 = R11 with the G4 (q,z) kernel's vmcnt ledger restored to
// R8's proven form (prologue vmcnt(3), tail 3/0/-1/-1 — R11 had vmcnt(6)
// and 3/3/0/-1, leaving tile 1 / tile NT-1 uncertified at first read).
// kv/e use the 8-phase BK=64 kernel (ledger audited race-free).
// ---------------------------------------------------------------------------

typedef __attribute__((ext_vector_type(8))) __bf16 bf16x8;
typedef __attribute__((ext_vector_type(4))) float f32x4;
typedef __attribute__((ext_vector_type(8))) unsigned short ushort8v;

#define S_DIM 4096
#define T_DIM 4096
#define D_DIM 2048

__device__ __forceinline__ unsigned short f2bf(float f) {
    unsigned int u = __float_as_uint(f);
    u += 0x7fffu + ((u >> 16) & 1u);
    return (unsigned short)(u >> 16);
}

__device__ __forceinline__ void block_sync() {
    __builtin_amdgcn_sched_barrier(0);
    __builtin_amdgcn_s_barrier();
    __builtin_amdgcn_sched_barrier(0);
}

#define GL(gptr, sptr)                                                        \
    __builtin_amdgcn_global_load_lds(                                         \
        (__attribute__((address_space(1))) void*)(void*)(gptr),               \
        (__attribute__((address_space(3))) void*)(sptr), 16, 0, 0)

__device__ __forceinline__ f32x4 MFMA16(bf16x8 a, bf16x8 b, f32x4 c) {
    return __builtin_amdgcn_mfma_f32_16x16x32_bf16(a, b, c, 0, 0, 0);
}

#define LD8(p) (*(const bf16x8*)(p))

// ---- f32 -> bf16 convert ---------------------------------------------------
__global__ __launch_bounds__(256)
void k_convert(const float* __restrict__ in, unsigned short* __restrict__ out, long n) {
    long i = ((long)blockIdx.x * blockDim.x + threadIdx.x) * 8;
    const long stride = (long)gridDim.x * blockDim.x * 8;
    for (; i < n; i += stride) {
        float4 a = *(const float4*)(in + i);
        float4 b = *(const float4*)(in + i + 4);
        ushort8v o;
        o[0] = f2bf(a.x); o[1] = f2bf(a.y); o[2] = f2bf(a.z); o[3] = f2bf(a.w);
        o[4] = f2bf(b.x); o[5] = f2bf(b.y); o[6] = f2bf(b.z); o[7] = f2bf(b.w);
        *(ushort8v*)(out + i) = o;
    }
}

// ---- fused: x f32 [R][C] -> bf16 x^T [C][R] AND bf16 x [R][C] ---------------
__global__ __launch_bounds__(256)
void k_transpose_dual(const float* __restrict__ in,
                      unsigned short* __restrict__ outT,
                      unsigned short* __restrict__ outN, int R, int C) {
    __shared__ float tile[32][33];
    const int bx = blockIdx.x * 32;
    const int by = blockIdx.y * 32;
    const int tx = threadIdx.x;
    const int ty = threadIdx.y;
    #pragma unroll
    for (int i = 0; i < 32; i += 8) {
        float v = in[(long)(by + ty + i) * C + bx + tx];
        tile[ty + i][tx] = v;
        outN[(long)(by + ty + i) * C + bx + tx] = f2bf(v);
    }
    __syncthreads();
    #pragma unroll
    for (int i = 0; i < 32; i += 8)
        outT[(long)(bx + ty + i) * R + by + tx] = f2bf(tile[tx][ty + i]);
}

// ---- transpose bf16 [R][C] -> bf16 [C][R] ----------------------------------
__global__ __launch_bounds__(256)
void k_transpose_bf(const unsigned short* __restrict__ in,
                    unsigned short* __restrict__ out, int R, int C) {
    __shared__ unsigned short tile[32][33];
    const int bx = blockIdx.x * 32;
    const int by = blockIdx.y * 32;
    const int tx = threadIdx.x;
    const int ty = threadIdx.y;
    #pragma unroll
    for (int i = 0; i < 32; i += 8)
        tile[ty + i][tx] = in[(long)(by + ty + i) * C + bx + tx];
    __syncthreads();
    #pragma unroll
    for (int i = 0; i < 32; i += 8)
        out[(long)(bx + ty + i) * R + by + tx] = tile[tx][ty + i];
}

// ============================================================================
// 8-phase kernel (kv, e): BM=BN=256, BK=64, 8 waves (2Mx4N), 2-dbuf 64KB.
// Buf layout: [A 32KB][B 32KB]; LDS byte = row*128 + ((chunk^(row&7))<<4).
// Phases P1..P4 per K-tile; reads P1:B1[t] P2:A1[t] P3:A0[t+1] P4:B0[t+1];
// stages P1:B-h1[t+1]->nxt, P2:B-h0[t+2]->cur, P3:A-h0[t+2]->cur,
// P4:A-h1[t+2]->cur. vmcnt(4)@P2,P3 (counted, never 0 mid-loop).
// ============================================================================
template<bool SP1, bool SP234, int V2, int V3, bool RD>
__device__ __forceinline__ void tile64(
    const unsigned short* __restrict__ pA, const unsigned short* __restrict__ pB,
    long K, char* cur, char* nxt, int tid, long k1, long k2,
    int arB0, int brB0,
    bf16x8 (&A0)[8], bf16x8 (&A1)[8], bf16x8 (&B0)[4], bf16x8 (&B1)[4],
    f32x4 (&acc)[8][4])
{
    const int arB1 = arB0 ^ 64;
    const int brB1 = brB0 ^ 64;
    // ---------------- P1 ----------------
    B1[0] = LD8(cur + brB0 + 4096);
    B1[1] = LD8(cur + brB1 + 4096);
    B1[2] = LD8(cur + brB0 + 6144);
    B1[3] = LD8(cur + brB1 + 6144);
    if constexpr (SP1) {
        GL(pB + 128 * K + k1, nxt + 49152 + tid * 16);
        GL(pB + 192 * K + k1, nxt + 57344 + tid * 16);
    }
    block_sync();
    asm volatile("s_waitcnt lgkmcnt(4)" ::: "memory");
    __builtin_amdgcn_sched_barrier(0);
    __builtin_amdgcn_s_setprio(1);
    #pragma unroll
    for (int ks = 0; ks < 2; ++ks)
        #pragma unroll
        for (int mi = 0; mi < 4; ++mi)
            #pragma unroll
            for (int ni = 0; ni < 2; ++ni)
                acc[mi][ni] = MFMA16(A0[mi * 2 + ks], B0[ni * 2 + ks], acc[mi][ni]);
    __builtin_amdgcn_s_setprio(0);
    // ---------------- P2 ----------------
    #pragma unroll
    for (int mi = 0; mi < 4; ++mi) {
        A1[mi * 2 + 0] = LD8(cur + arB0 + (4 + mi) * 2048);
        A1[mi * 2 + 1] = LD8(cur + arB1 + (4 + mi) * 2048);
    }
    if constexpr (SP234) {
        GL(pB + k2, cur + 32768 + tid * 16);
        GL(pB + 64 * K + k2, cur + 40960 + tid * 16);
    }
    if constexpr (V2 == 4)      asm volatile("s_waitcnt vmcnt(4)" ::: "memory");
    else if constexpr (V2 == 2) asm volatile("s_waitcnt vmcnt(2)" ::: "memory");
    block_sync();
    asm volatile("s_waitcnt lgkmcnt(8)" ::: "memory");
    __builtin_amdgcn_sched_barrier(0);
    __builtin_amdgcn_s_setprio(1);
    #pragma unroll
    for (int ks = 0; ks < 2; ++ks)
        #pragma unroll
        for (int mi = 0; mi < 4; ++mi)
            #pragma unroll
            for (int ni = 0; ni < 2; ++ni)
                acc[mi][2 + ni] = MFMA16(A0[mi * 2 + ks], B1[ni * 2 + ks], acc[mi][2 + ni]);
    __builtin_amdgcn_s_setprio(0);
    // ---------------- P3 ----------------
    if constexpr (RD) {
        #pragma unroll
        for (int mi = 0; mi < 4; ++mi) {
            A0[mi * 2 + 0] = LD8(nxt + arB0 + mi * 2048);
            A0[mi * 2 + 1] = LD8(nxt + arB1 + mi * 2048);
        }
    }
    if constexpr (SP234) {
        GL(pA + k2, cur + tid * 16);
        GL(pA + 64 * K + k2, cur + 8192 + tid * 16);
    }
    if constexpr (V3 == 4)      asm volatile("s_waitcnt vmcnt(4)" ::: "memory");
    else if constexpr (V3 == 0) asm volatile("s_waitcnt vmcnt(0)" ::: "memory");
    block_sync();
    if constexpr (RD) asm volatile("s_waitcnt lgkmcnt(8)" ::: "memory");
    else              asm volatile("s_waitcnt lgkmcnt(0)" ::: "memory");
    __builtin_amdgcn_sched_barrier(0);
    __builtin_amdgcn_s_setprio(1);
    #pragma unroll
    for (int ks = 0; ks < 2; ++ks)
        #pragma unroll
        for (int mi = 0; mi < 4; ++mi)
            #pragma unroll
            for (int ni = 0; ni < 2; ++ni)
                acc[4 + mi][ni] = MFMA16(A1[mi * 2 + ks], B0[ni * 2 + ks], acc[4 + mi][ni]);
    __builtin_amdgcn_s_setprio(0);
    // ---------------- P4 ----------------
    if constexpr (RD) {
        B0[0] = LD8(nxt + brB0);
        B0[1] = LD8(nxt + brB1);
        B0[2] = LD8(nxt + brB0 + 2048);
        B0[3] = LD8(nxt + brB1 + 2048);
    }
    if constexpr (SP234) {
        GL(pA + 128 * K + k2, cur + 16384 + tid * 16);
        GL(pA + 192 * K + k2, cur + 24576 + tid * 16);
    }
    block_sync();
    __builtin_amdgcn_s_setprio(1);
    #pragma unroll
    for (int ks = 0; ks < 2; ++ks)
        #pragma unroll
        for (int mi = 0; mi < 4; ++mi)
            #pragma unroll
            for (int ni = 0; ni < 2; ++ni)
                acc[4 + mi][2 + ni] = MFMA16(A1[mi * 2 + ks], B1[ni * 2 + ks], acc[4 + mi][2 + ni]);
    __builtin_amdgcn_s_setprio(0);
}

template<int OUT_BF16>
__global__ __launch_bounds__(512, 2)
void k_gemm8(const unsigned short* __restrict__ A,
             const unsigned short* __restrict__ B,
             void* __restrict__ C,
             int M, int N, int K, float alpha) {
    extern __shared__ __align__(16) char smem[];
    const int tid = threadIdx.x;
    const int l = tid & 63;
    const int w = tid >> 6;
    const int wr = w >> 2;                   // 0..1
    const int wc = w & 3;                    // 0..3

    // XCD-chunked + 4-col supertile block swizzle (grid 256, gx%4==0)
    const int gx = gridDim.x, gy = gridDim.y;
    const int flat = blockIdx.y * gx + blockIdx.x;
    const int per = (gx * gy) >> 3;
    const int wid = (flat & 7) * per + (flat >> 3);
    const int sc = wid / (gy * 4);
    const int rm = wid - sc * gy * 4;
    const int by = rm >> 2;
    const int bx = sc * 4 + (rm & 3);

    const long brow = (long)by * 256;
    const long bcol = (long)bx * 256;
    const int NT = K >> 6;
    const long Kl = K;

    // staging: per-thread granule row R0 = tid>>3, chunk C0 = (tid&7)^(R0&7)
    const int R0 = tid >> 3;
    const int C0 = (tid & 7) ^ (R0 & 7);
    const unsigned short* pA = A + (brow + R0) * Kl + C0 * 8;
    const unsigned short* pB = B + (bcol + R0) * Kl + C0 * 8;

    // ds_read bases: row*128 + ((chunk^(row&7))<<4); ks=1 -> ^64
    const int slot0 = (((l >> 4) ^ (l & 7)) << 4);
    const int arB0 = (wr * 128 + (l & 15)) * 128 + slot0;
    const int brB0 = 32768 + (wc * 64 + (l & 15)) * 128 + slot0;

    char* s0 = smem;
    char* s1 = smem + 65536;

    bf16x8 A0[8], A1[8], B0[4], B1[4];
    f32x4 acc[8][4] = {};

    // ---- prologue: tile0 (4 halves each), then B-h0/A-h0/A-h1 of tile 1 ----
    GL(pB,                 s0 + 32768 + tid * 16);
    GL(pB + 64 * Kl,       s0 + 40960 + tid * 16);
    GL(pB + 128 * Kl,      s0 + 49152 + tid * 16);
    GL(pB + 192 * Kl,      s0 + 57344 + tid * 16);
    GL(pA,                 s0 + tid * 16);
    GL(pA + 64 * Kl,       s0 + 8192 + tid * 16);
    GL(pA + 128 * Kl,      s0 + 16384 + tid * 16);
    GL(pA + 192 * Kl,      s0 + 24576 + tid * 16);
    GL(pB + 64,            s1 + 32768 + tid * 16);
    GL(pB + 64 * Kl + 64,  s1 + 40960 + tid * 16);
    GL(pA + 64,            s1 + tid * 16);
    GL(pA + 64 * Kl + 64,  s1 + 8192 + tid * 16);
    GL(pA + 128 * Kl + 64, s1 + 16384 + tid * 16);
    GL(pA + 192 * Kl + 64, s1 + 24576 + tid * 16);
    asm volatile("s_waitcnt vmcnt(6)" ::: "memory");
    block_sync();
    #pragma unroll
    for (int mi = 0; mi < 4; ++mi) {
        A0[mi * 2 + 0] = LD8(s0 + arB0 + mi * 2048);
        A0[mi * 2 + 1] = LD8(s0 + (arB0 ^ 64) + mi * 2048);
    }
    B0[0] = LD8(s0 + brB0);
    B0[1] = LD8(s0 + (brB0 ^ 64));
    B0[2] = LD8(s0 + brB0 + 2048);
    B0[3] = LD8(s0 + (brB0 ^ 64) + 2048);

    // ---- main loop ----
    char* cur = s0;
    char* nxt = s1;
    for (int t = 0; t < NT - 2; ++t) {
        tile64<true, true, 4, 4, true>(pA, pB, Kl, cur, nxt, tid,
                                       (long)(t + 1) << 6, (long)(t + 2) << 6,
                                       arB0, brB0, A0, A1, B0, B1, acc);
        char* tp = cur; cur = nxt; nxt = tp;
    }
    tile64<true, false, 2, 0, true>(pA, pB, Kl, cur, nxt, tid,
                                    (long)(NT - 1) << 6, 0,
                                    arB0, brB0, A0, A1, B0, B1, acc);
    { char* tp = cur; cur = nxt; nxt = tp; }
    tile64<false, false, -1, -1, false>(pA, pB, Kl, cur, nxt, tid, 0, 0,
                                        arB0, brB0, A0, A1, B0, B1, acc);

    // ---- epilogue: C/D layout col = lane&15, row = (lane>>4)*4 + reg -------
    const long crow0 = brow + wr * 128 + (l >> 4) * 4;
    const long ccol0 = bcol + wc * 64 + (l & 15);
    #pragma unroll
    for (int n = 0; n < 4; ++n) {
        const long col = ccol0 + n * 16;
        #pragma unroll
        for (int m = 0; m < 8; ++m) {
            #pragma unroll
            for (int r = 0; r < 4; ++r) {
                const long row = crow0 + m * 16 + r;
                const float v = acc[m][n][r] * alpha;
                if (OUT_BF16)
                    ((unsigned short*)C)[row * N + col] = f2bf(v);
                else
                    ((float*)C)[row * N + col] = v;
            }
        }
    }
}

// ============================================================================
// R8 ring-4 kernel (q, z): BM=128, BN=256, BK=32, 8 waves, 2 phases/tile.
// Prologue vmcnt(3) (certifies tiles 0,1); tail 3/0/-1/-1 — R8's exact form.
// ============================================================================
template<bool STG, bool PF, int VMW>
__device__ __forceinline__ void seg4(
    const unsigned short* (&gA)[1], const int (&ldA)[1],
    const unsigned short* (&gB)[2], const int (&ldB)[2],
    const char* cur, const char* nxt, char* stg, int arB, int brB,
    bf16x8 (&Ac)[4], bf16x8 (&B01c)[2], bf16x8 (&B23)[2],
    bf16x8 (&An)[4], bf16x8 (&B01n)[2],
    f32x4 (&acc)[4][4])
{
    B23[0] = LD8(cur + brB + 2048);
    B23[1] = LD8(cur + brB + 3072);
    if constexpr (STG) {
        GL(gA[0], stg + ldA[0]); gA[0] += 32;
    }
    block_sync();
    asm volatile("s_waitcnt lgkmcnt(2)" ::: "memory");
    __builtin_amdgcn_sched_barrier(0);
    __builtin_amdgcn_s_setprio(1);
    #pragma unroll
    for (int m = 0; m < 4; ++m) {
        acc[m][0] = MFMA16(Ac[m], B01c[0], acc[m][0]);
        acc[m][1] = MFMA16(Ac[m], B01c[1], acc[m][1]);
    }
    __builtin_amdgcn_s_setprio(0);
    if constexpr (PF) {
        #pragma unroll
        for (int m = 0; m < 4; ++m)
            An[m] = LD8(nxt + arB + m * 1024);
        B01n[0] = LD8(nxt + brB);
        B01n[1] = LD8(nxt + brB + 1024);
    }
    if constexpr (STG) {
        GL(gB[0], stg + ldB[0]); gB[0] += 32;
        GL(gB[1], stg + ldB[1]); gB[1] += 32;
    }
    if constexpr (VMW == 3)      asm volatile("s_waitcnt vmcnt(3)" ::: "memory");
    else if constexpr (VMW == 0) asm volatile("s_waitcnt vmcnt(0)" ::: "memory");
    block_sync();
    if constexpr (PF) asm volatile("s_waitcnt lgkmcnt(6)" ::: "memory");
    else              asm volatile("s_waitcnt lgkmcnt(0)" ::: "memory");
    __builtin_amdgcn_sched_barrier(0);
    __builtin_amdgcn_s_setprio(1);
    #pragma unroll
    for (int m = 0; m < 4; ++m) {
        acc[m][2] = MFMA16(Ac[m], B23[0], acc[m][2]);
        acc[m][3] = MFMA16(Ac[m], B23[1], acc[m][3]);
    }
    __builtin_amdgcn_s_setprio(0);
}

template<int OUT_BF16, int HAS_BIAS>
__global__ __launch_bounds__(512, 2)
void k_gemm(const unsigned short* __restrict__ A,
            const unsigned short* __restrict__ B,
            const float* __restrict__ bias,
            void* __restrict__ C,
            int M, int N, int K, float alpha) {
    constexpr int LDSA = 128 * 64;
    constexpr int SLOT = LDSA + 16384;
    extern __shared__ __align__(16) char smem[];

    const int tid = threadIdx.x;
    const int l = tid & 63;
    const int w = tid >> 6;
    const int wr = w >> 2;
    const int wc = w & 3;

    const int gx = gridDim.x, gy = gridDim.y;
    const int flat = blockIdx.y * gx + blockIdx.x;
    const int per = (gx * gy) >> 3;
    const int wid = (flat & 7) * per + (flat >> 3);
    const int sc = wid / (gy * 4);
    const int rm = wid - sc * gy * 4;
    const int by = rm >> 2;
    const int bx = sc * 4 + (rm & 3);

    const long brow = (long)by * 128;
    const long bcol = (long)bx * 256;
    const int NT = K >> 5;

    const unsigned short* gA[1];
    int ldA[1];
    {
        const int q = w * 64 + l;
        const int R = q >> 2;
        const int c = (q & 3) ^ ((R >> 1) & 3);
        gA[0] = A + (brow + R) * (long)K + c * 8;
        ldA[0] = q * 16;
    }
    const unsigned short* gB[2];
    int ldB[2];
    #pragma unroll
    for (int j = 0; j < 2; ++j) {
        const int q = (w * 2 + j) * 64 + l;
        const int R = q >> 2;
        const int c = (q & 3) ^ ((R >> 1) & 3);
        gB[j] = B + (bcol + R) * (long)K + c * 8;
        ldB[j] = LDSA + q * 16;
    }

    const int sAB = (((l >> 4) ^ ((l >> 1) & 3)) << 4);
    const int arB = (wr * 64 + (l & 15)) * 64 + sAB;
    const int brB = LDSA + (wc * 64 + (l & 15)) * 64 + sAB;

    char* const b0 = smem;
    char* const b1 = smem + SLOT;
    char* const b2 = smem + 2 * SLOT;
    char* const b3 = smem + 3 * SLOT;

    {
        char* d = smem;
        #pragma unroll
        for (int tt = 0; tt < 3; ++tt) {
            GL(gA[0], d + ldA[0]); gA[0] += 32;
            #pragma unroll
            for (int j = 0; j < 2; ++j) { GL(gB[j], d + ldB[j]); gB[j] += 32; }
            d += SLOT;
        }
        asm volatile("s_waitcnt vmcnt(3)" ::: "memory");   // certify tiles 0 AND 1
        block_sync();
    }

    bf16x8 Aa[4], Ab[4], Ba[2], Bb[2], B23[2];
    #pragma unroll
    for (int m = 0; m < 4; ++m) Aa[m] = LD8(b0 + arB + m * 1024);
    Ba[0] = LD8(b0 + brB);
    Ba[1] = LD8(b0 + brB + 1024);

    f32x4 acc[4][4] = {};
    for (int t = 0; t + 8 <= NT; t += 4) {
        seg4<true, true, 3>(gA, ldA, gB, ldB, b0, b1, b3, arB, brB,
                            Aa, Ba, B23, Ab, Bb, acc);
        seg4<true, true, 3>(gA, ldA, gB, ldB, b1, b2, b0, arB, brB,
                            Ab, Bb, B23, Aa, Ba, acc);
        seg4<true, true, 3>(gA, ldA, gB, ldB, b2, b3, b1, arB, brB,
                            Aa, Ba, B23, Ab, Bb, acc);
        seg4<true, true, 3>(gA, ldA, gB, ldB, b3, b0, b2, arB, brB,
                            Ab, Bb, B23, Aa, Ba, acc);
    }
    // tail: tiles NT-4 .. NT-1 (R8's exact ledger)
    seg4<true,  true,  3>(gA, ldA, gB, ldB, b0, b1, b3, arB, brB,
                          Aa, Ba, B23, Ab, Bb, acc);
    seg4<false, true,  0>(gA, ldA, gB, ldB, b1, b2, b3, arB, brB,
                          Ab, Bb, B23, Aa, Ba, acc);
    seg4<false, true, -1>(gA, ldA, gB, ldB, b2, b3, b3, arB, brB,
                          Aa, Ba, B23, Ab, Bb, acc);
    seg4<false, false, -1>(gA, ldA, gB, ldB, b3, b0, b3, arB, brB,
                           Ab, Bb, B23, Aa, Ba, acc);

    const long crow0 = brow + wr * 64 + (l >> 4) * 4;
    const long ccol0 = bcol + wc * 64 + (l & 15);
    #pragma unroll
    for (int n = 0; n < 4; ++n) {
        const long col = ccol0 + n * 16;
        const float bb = HAS_BIAS ? bias[col] : 0.0f;
        #pragma unroll
        for (int m = 0; m < 4; ++m) {
            #pragma unroll
            for (int r = 0; r < 4; ++r) {
                const long row = crow0 + m * 16 + r;
                const float v = acc[m][n][r] * alpha + bb;
                if (OUT_BF16)
                    ((unsigned short*)C)[row * N + col] = f2bf(v);
                else
                    ((float*)C)[row * N + col] = v;
            }
        }
    }
}

// ---- row softmax: e [S][T] bf16 -> a [S][T] bf16 ----------------------------
__global__ __launch_bounds__(256)
void k_softmax_bf(const unsigned short* __restrict__ E,
                  unsigned short* __restrict__ A, int T) {
    const long row = blockIdx.x;
    const unsigned short* er = E + row * (long)T;
    const int t = threadIdx.x;
    const int l = t & 63;
    const int w = t >> 6;

    float v[16];
    float m = -3.4e38f;
    #pragma unroll
    for (int j = 0; j < 2; ++j) {
        ushort8v u = *(const ushort8v*)(er + j * 2048 + t * 8);
        #pragma unroll
        for (int i = 0; i < 8; ++i) {
            v[j * 8 + i] = __uint_as_float((unsigned int)u[i] << 16);
            m = fmaxf(m, v[j * 8 + i]);
        }
    }
    #pragma unroll
    for (int o = 32; o > 0; o >>= 1) m = fmaxf(m, __shfl_xor(m, o));

    __shared__ float redm[4];
    __shared__ float reds[4];
    if (l == 0) redm[w] = m;
    __syncthreads();
    m = fmaxf(fmaxf(redm[0], redm[1]), fmaxf(redm[2], redm[3]));

    float s = 0.f;
    #pragma unroll
    for (int i = 0; i < 16; ++i) {
        v[i] = __expf(v[i] - m);
        s += v[i];
    }
    #pragma unroll
    for (int o = 32; o > 0; o >>= 1) s += __shfl_xor(s, o);
    if (l == 0) reds[w] = s;
    __syncthreads();
    s = reds[0] + reds[1] + reds[2] + reds[3];
    const float inv = 1.0f / s;

    unsigned short* ar = A + row * (long)T;
    #pragma unroll
    for (int j = 0; j < 2; ++j) {
        ushort8v o8;
        #pragma unroll
        for (int i = 0; i < 8; ++i) o8[i] = f2bf(v[j * 8 + i] * inv);
        *(ushort8v*)(ar + j * 2048 + t * 8) = o8;
    }
}

// ---------------------------------------------------------------------------
extern "C" void kernel_launch(void* const* d_in, const int* in_sizes, int n_in,
                              void* d_out, int out_size, void* d_ws, size_t ws_size,
                              hipStream_t stream) {
    const float* x   = (const float*)d_in[0];   // [S][D]
    const float* enc = (const float*)d_in[1];   // [2][T][S]
    const float* Wq  = (const float*)d_in[2];   // [D][D]
    const float* bq  = (const float*)d_in[3];   // [D]
    float* out = (float*)d_out;                 // [S][D]
    char* ws = (char*)d_ws;

    unsigned short* abf   = (unsigned short*)(ws);                 // [S][T]   32MB (late)
    unsigned short* xT    = (unsigned short*)(ws);                 // [D][S]   16MB (early)
    unsigned short* xbf   = (unsigned short*)(ws + (16L << 20));   // [S][D]   16MB (early)
    unsigned short* wqbf  = (unsigned short*)(ws + (32L << 20));   // [D][D]    8MB
    unsigned short* qbf   = (unsigned short*)(ws + (40L << 20));   // [S][D]   16MB
    unsigned short* kv    = (unsigned short*)(ws + (56L << 20));   // [2T][D]  32MB
    unsigned short* vT    = (unsigned short*)(ws + (88L << 20));   // [D][T]   16MB
    unsigned short* encbf = (unsigned short*)(ws + (104L << 20));  // [2][T][S] 64MB (early)
    unsigned short* ebf   = (unsigned short*)(ws + (104L << 20));  // [S][T]   32MB (reuse)

    k_convert<<<4096, 256, 0, stream>>>(Wq,  wqbf,  (long)D_DIM * D_DIM);
    k_convert<<<4096, 256, 0, stream>>>(enc, encbf, 2L * T_DIM * S_DIM);
    k_transpose_dual<<<dim3(D_DIM / 32, S_DIM / 32), dim3(32, 8), 0, stream>>>(
        x, xT, xbf, S_DIM, D_DIM);

    #define LAUNCH_G4(OB, HB, Ap, Bp, biasp, Cp, M_, N_, K_, al)                           \
        do {                                                                               \
            constexpr int smemB = (128 * 64 + 16384) * 4;                                  \
            hipFuncSetAttribute((const void*)k_gemm<OB, HB>,                               \
                                hipFuncAttributeMaxDynamicSharedMemorySize, smemB);        \
            k_gemm<OB, HB><<<dim3((N_) / 256, (M_) / 128), 512, smemB, stream>>>(          \
                Ap, Bp, biasp, Cp, M_, N_, K_, al);                                        \
        } while (0)

    #define LAUNCH_G8(OB, Ap, Bp, Cp, M_, N_, K_, al)                                      \
        do {                                                                               \
            hipFuncSetAttribute((const void*)k_gemm8<OB>,                                  \
                                hipFuncAttributeMaxDynamicSharedMemorySize, 131072);       \
            k_gemm8<OB><<<dim3((N_) / 256, (M_) / 256), 512, 131072, stream>>>(            \
                Ap, Bp, Cp, M_, N_, K_, al);                                               \
        } while (0)

    // q = x @ Wq^T + bq            [4096,2048]  grid (8,32)
    LAUNCH_G4(1, 1, xbf, wqbf, bq, qbf, S_DIM, D_DIM, D_DIM, 1.0f);
    // kv = enc @ xT^T              [8192,2048]  grid (8,32)
    LAUNCH_G8(1, encbf, xT, kv, 2 * T_DIM, D_DIM, S_DIM, 1.0f);
    // vT = transpose(v)            [2048,4096]
    k_transpose_bf<<<dim3(D_DIM / 32, T_DIM / 32), dim3(32, 8), 0, stream>>>(
        kv + (long)T_DIM * D_DIM, vT, T_DIM, D_DIM);
    // e = q @ k^T / sqrt(D)        [4096,4096]  grid (16,16), bf16 out
    LAUNCH_G8(1, qbf, kv, ebf, S_DIM, T_DIM, D_DIM, 0.022097086912079608f);
    // a = softmax(e)               [S,T] bf16
    k_softmax_bf<<<S_DIM, 256, 0, stream>>>(ebf, abf, T_DIM);
    // z = a @ vT^T                 [4096,2048]  grid (8,32), fp32 -> d_out
    LAUNCH_G4(0, 0, abf, vT, nullptr, out, S_DIM, D_DIM, T_DIM, 1.0f);
}